// Round 1
// baseline (487.513 us; speedup 1.0000x reference)
//
#include <hip/hip_runtime.h>
#include <hip/hip_bf16.h>

// Head: B=16, T=2048, C=1024, H=128. out fp32 [B,T,H].
// ws layout: Wt bf16 [384][1024] | qk bf16 [32768][256] (q cols 0..127, k 128..255) | Vt bf16 [16][128][2048]

typedef __bf16 bf16x8 __attribute__((ext_vector_type(8)));
typedef __bf16 bf16x4 __attribute__((ext_vector_type(4)));
typedef float  f32x4  __attribute__((ext_vector_type(4)));

#define MFMA16(a, b, c) __builtin_amdgcn_mfma_f32_16x16x32_bf16((a), (b), (c), 0, 0, 0)

#if __has_builtin(__builtin_amdgcn_exp2f)
#define EXP2F __builtin_amdgcn_exp2f
#else
#define EXP2F exp2f
#endif

#define LOG2E 1.4426950408889634f

static __device__ __forceinline__ bf16x8 pack8(float4 a, float4 b) {
  bf16x8 r;
  r[0] = (__bf16)a.x; r[1] = (__bf16)a.y; r[2] = (__bf16)a.z; r[3] = (__bf16)a.w;
  r[4] = (__bf16)b.x; r[5] = (__bf16)b.y; r[6] = (__bf16)b.z; r[7] = (__bf16)b.w;
  return r;
}

// ---------- Wt[n][c] = W_{n/128}[c][n%128]  (Wq scaled by H^-0.5) ----------
__global__ __launch_bounds__(256) void k_build_wt(
    const float* __restrict__ Wq, const float* __restrict__ Wk,
    const float* __restrict__ Wv, __bf16* __restrict__ Wt)
{
  __shared__ float tile[32][33];
  const int tx = threadIdx.x, ty = threadIdx.y;
  const int c0 = blockIdx.x * 32, h0 = blockIdx.y * 32, w = blockIdx.z;
  const float* W = (w == 0) ? Wq : (w == 1) ? Wk : Wv;
  const float s = (w == 0) ? 0.08838834764831843f : 1.0f;
#pragma unroll
  for (int i = 0; i < 4; ++i)
    tile[ty + i * 8][tx] = W[(size_t)(c0 + ty + i * 8) * 128 + h0 + tx];
  __syncthreads();
#pragma unroll
  for (int i = 0; i < 4; ++i)
    Wt[(size_t)(w * 128 + h0 + ty + i * 8) * 1024 + c0 + tx] =
        (__bf16)(tile[tx][ty + i * 8] * s);
}

// ---------- fused QKV projection: [64 rows] x [all 384 cols] per block ----------
// A (x) reg-staged fp32->bf16 into swizzled LDS; B (Wt) frags direct from L2.
__global__ __launch_bounds__(256) void k_proj(
    const float* __restrict__ x, const __bf16* __restrict__ Wt,
    __bf16* __restrict__ qk, __bf16* __restrict__ Vt)
{
  const int tid  = threadIdx.x;
  const int lane = tid & 63, wid = tid >> 6;
  const int lr = lane & 15, g = lane >> 4;
  const int m0 = blockIdx.x * 64;

  __shared__ __bf16 As[2][2][64][32];  // [buf][kk][row][col], col XOR-swizzled

  const int srow = tid >> 2;           // 0..63
  const int cs   = (tid & 3) * 16;     // 0,16,32,48
  const int skk  = cs >> 5;
  const int scol = cs & 31;
  const int sswz = ((srow >> 1) & 3) << 3;
  const float* xrow = x + (size_t)(m0 + srow) * 1024 + cs;

  const int nbase = wid * 96;          // wave owns 96 N-cols
  f32x4 acc[4][6] = {};

  for (int kt = 0; kt < 16; ++kt) {
    const int k0 = kt * 64;
    float4 a0 = *(const float4*)(xrow + k0);
    float4 a1 = *(const float4*)(xrow + k0 + 4);
    float4 a2 = *(const float4*)(xrow + k0 + 8);
    float4 a3 = *(const float4*)(xrow + k0 + 12);
    const int buf = kt & 1;
    *(bf16x8*)&As[buf][skk][srow][scol ^ sswz]       = pack8(a0, a1);
    *(bf16x8*)&As[buf][skk][srow][(scol + 8) ^ sswz] = pack8(a2, a3);
    __syncthreads();  // single barrier per K-step (double-buffered LDS)
#pragma unroll
    for (int kk = 0; kk < 2; ++kk) {
      bf16x8 af[4];
#pragma unroll
      for (int i = 0; i < 4; ++i) {
        const int row = i * 16 + lr;
        af[i] = *(const bf16x8*)&As[buf][kk][row][(g * 8) ^ (((row >> 1) & 3) << 3)];
      }
#pragma unroll
      for (int j = 0; j < 6; ++j) {
        const bf16x8 bfr = *(const bf16x8*)(
            Wt + (size_t)(nbase + j * 16 + lr) * 1024 + k0 + kk * 32 + g * 8);
#pragma unroll
        for (int i = 0; i < 4; ++i)
          acc[i][j] = MFMA16(af[i], bfr, acc[i][j]);
      }
    }
  }

  // epilogue: n<256 -> qk[m][n]; n>=256 -> Vt[b][n-256][t] (4 consecutive t packed)
  const int b  = m0 >> 11;
  const int t0 = m0 & 2047;
#pragma unroll
  for (int j = 0; j < 6; ++j) {
    const int n = nbase + j * 16 + lr;
    if (nbase + j * 16 < 256) {
#pragma unroll
      for (int i = 0; i < 4; ++i) {
        const size_t mr = (size_t)(m0 + i * 16 + g * 4);
#pragma unroll
        for (int rr = 0; rr < 4; ++rr)
          qk[(mr + rr) * 256 + n] = (__bf16)acc[i][j][rr];
      }
    } else {
      const int d = n - 256;
#pragma unroll
      for (int i = 0; i < 4; ++i) {
        const int t = t0 + i * 16 + g * 4;
        bf16x4 pv;
        pv[0] = (__bf16)acc[i][j][0]; pv[1] = (__bf16)acc[i][j][1];
        pv[2] = (__bf16)acc[i][j][2]; pv[3] = (__bf16)acc[i][j][3];
        *(bf16x4*)(Vt + ((size_t)(b * 128 + d)) * 2048 + t) = pv;
      }
    }
  }
}

// ---------- causal flash attention: 4 independent waves/block, 16 q-rows each ----------
__global__ __launch_bounds__(256) void k_attn(
    const __bf16* __restrict__ qk, const __bf16* __restrict__ Vt,
    float* __restrict__ out)
{
  const int tid  = threadIdx.x;
  const int lane = tid & 63, wid = tid >> 6;
  const int lr = lane & 15, g = lane >> 4;
  const int b  = blockIdx.y;
  const int q0 = (int)(gridDim.x - 1 - blockIdx.x) * 64 + wid * 16;  // heavy blocks first

  __shared__ __bf16 Plds[4][16][32];   // per-wave P buffer

  const __bf16* qkb = qk + (size_t)b * 2048 * 256;
  const __bf16* vtb = Vt + (size_t)b * 128 * 2048;

  bf16x8 qf[4];
#pragma unroll
  for (int d4 = 0; d4 < 4; ++d4)
    qf[d4] = *(const bf16x8*)(qkb + (size_t)(q0 + lr) * 256 + d4 * 32 + g * 8);

  f32x4 o[8] = {};
  float m[4], l[4];
#pragma unroll
  for (int r = 0; r < 4; ++r) { m[r] = -1e30f; l[r] = 0.0f; }

  const int kvlast = q0 & ~31;
  for (int kv0 = 0; kv0 <= kvlast; kv0 += 32) {
    f32x4 s0 = {}, s1 = {};
#pragma unroll
    for (int d4 = 0; d4 < 4; ++d4) {
      const bf16x8 k0f = *(const bf16x8*)(qkb + (size_t)(kv0 + lr)      * 256 + 128 + d4 * 32 + g * 8);
      const bf16x8 k1f = *(const bf16x8*)(qkb + (size_t)(kv0 + 16 + lr) * 256 + 128 + d4 * 32 + g * 8);
      s0 = MFMA16(qf[d4], k0f, s0);
      s1 = MFMA16(qf[d4], k1f, s1);
    }
    if (kv0 == kvlast) {   // diagonal tile: causal mask
#pragma unroll
      for (int rr = 0; rr < 4; ++rr) {
        const int qrow = q0 + g * 4 + rr;
        if (kv0 + lr > qrow)      s0[rr] = -1e30f;
        if (kv0 + 16 + lr > qrow) s1[rr] = -1e30f;
      }
    }
    float ps_scale[4];
#pragma unroll
    for (int rr = 0; rr < 4; ++rr) {
      float mx = fmaxf(s0[rr], s1[rr]);
      mx = fmaxf(mx, __shfl_xor(mx, 1));
      mx = fmaxf(mx, __shfl_xor(mx, 2));
      mx = fmaxf(mx, __shfl_xor(mx, 4));
      mx = fmaxf(mx, __shfl_xor(mx, 8));
      const float mnew = fmaxf(m[rr], mx);
      const float al = EXP2F((m[rr] - mnew) * LOG2E);
      const float p0 = EXP2F((s0[rr] - mnew) * LOG2E);
      const float p1 = EXP2F((s1[rr] - mnew) * LOG2E);
      m[rr] = mnew;
      float ps = p0 + p1;
      ps += __shfl_xor(ps, 1);
      ps += __shfl_xor(ps, 2);
      ps += __shfl_xor(ps, 4);
      ps += __shfl_xor(ps, 8);
      l[rr] = l[rr] * al + ps;
      ps_scale[rr] = al;
      Plds[wid][g * 4 + rr][lr]      = (__bf16)p0;
      Plds[wid][g * 4 + rr][16 + lr] = (__bf16)p1;
    }
#pragma unroll
    for (int dt = 0; dt < 8; ++dt) {
#pragma unroll
      for (int rr = 0; rr < 4; ++rr) o[dt][rr] *= ps_scale[rr];
    }
    // wave-local fence: writes above, cross-lane read below (rule 18)
    asm volatile("s_waitcnt lgkmcnt(0)" ::: "memory");
    __builtin_amdgcn_sched_barrier(0);
    const bf16x8 pa = *(const bf16x8*)&Plds[wid][lr][g * 8];
#pragma unroll
    for (int dt = 0; dt < 8; ++dt) {
      const bf16x8 vf = *(const bf16x8*)(vtb + (size_t)(dt * 16 + lr) * 2048 + kv0 + g * 8);
      o[dt] = MFMA16(pa, vf, o[dt]);
    }
  }

  float* ob = out + ((size_t)b * 2048 + q0) * 128;
#pragma unroll
  for (int rr = 0; rr < 4; ++rr) {
    const float inv = 1.0f / l[rr];
#pragma unroll
    for (int dt = 0; dt < 8; ++dt)
      ob[(g * 4 + rr) * 128 + dt * 16 + lr] = o[dt][rr] * inv;
  }
}

extern "C" void kernel_launch(void* const* d_in, const int* in_sizes, int n_in,
                              void* d_out, int out_size, void* d_ws, size_t ws_size,
                              hipStream_t stream) {
  const float* x  = (const float*)d_in[0];
  const float* Wq = (const float*)d_in[1];
  const float* Wk = (const float*)d_in[2];
  const float* Wv = (const float*)d_in[3];
  float* out = (float*)d_out;

  char* ws = (char*)d_ws;
  __bf16* Wt  = (__bf16*)(ws);                              //   786,432 B
  __bf16* qkb = (__bf16*)(ws + 786432);                     // 16,777,216 B
  __bf16* Vt  = (__bf16*)(ws + 786432 + 16777216);          //  8,388,608 B

  k_build_wt<<<dim3(32, 4, 3), dim3(32, 8), 0, stream>>>(Wq, Wk, Wv, Wt);
  k_proj    <<<dim3(512),      dim3(256),  0, stream>>>(x, Wt, qkb, Vt);
  k_attn    <<<dim3(32, 16),   dim3(256),  0, stream>>>(qkb, Vt, out);
}

// Round 3
// 397.636 us; speedup vs baseline: 1.2260x; 1.2260x over previous
//
#include <hip/hip_runtime.h>
#include <hip/hip_bf16.h>
#include <stdint.h>

// Head: B=16, T=2048, C=1024, H=128. out fp32 [B,T,H].
// ws: Wt bf16 [384][1024] | qk bf16 [32768][256] (q:0..127, k:128..255) | Vt bf16 [16][128][2048]

typedef __bf16 bf16x8 __attribute__((ext_vector_type(8)));
typedef __bf16 bf16x4 __attribute__((ext_vector_type(4)));
typedef float  f32x4  __attribute__((ext_vector_type(4)));
typedef uint32_t u32;

#define MFMA16(a, b, c) __builtin_amdgcn_mfma_f32_16x16x32_bf16((a), (b), (c), 0, 0, 0)
#define LOG2E 1.4426950408889634f

static __device__ __forceinline__ float exp2fast(float x) { return __builtin_exp2f(x); }

static __device__ __forceinline__ bf16x8 pack8(float4 a, float4 b) {
  bf16x8 r;
  r[0] = (__bf16)a.x; r[1] = (__bf16)a.y; r[2] = (__bf16)a.z; r[3] = (__bf16)a.w;
  r[4] = (__bf16)b.x; r[5] = (__bf16)b.y; r[6] = (__bf16)b.z; r[7] = (__bf16)b.w;
  return r;
}

static __device__ __forceinline__ u32 pkbf16(float a, float b) {
  union { __bf16 h[2]; u32 u; } t;
  t.h[0] = (__bf16)a; t.h[1] = (__bf16)b;
  return t.u;
}

// ---------- Wt[n][c] = W_{n/128}[c][n%128]  (Wq scaled by H^-0.5) ----------
__global__ __launch_bounds__(256) void k_build_wt(
    const float* __restrict__ Wq, const float* __restrict__ Wk,
    const float* __restrict__ Wv, __bf16* __restrict__ Wt)
{
  __shared__ float tile[32][33];
  const int tx = threadIdx.x, ty = threadIdx.y;
  const int c0 = blockIdx.x * 32, h0 = blockIdx.y * 32, w = blockIdx.z;
  const float* W = (w == 0) ? Wq : (w == 1) ? Wk : Wv;
  const float s = (w == 0) ? 0.08838834764831843f : 1.0f;
#pragma unroll
  for (int i = 0; i < 4; ++i)
    tile[ty + i * 8][tx] = W[(size_t)(c0 + ty + i * 8) * 128 + h0 + tx];
  __syncthreads();
#pragma unroll
  for (int i = 0; i < 4; ++i)
    Wt[(size_t)(w * 128 + h0 + ty + i * 8) * 1024 + c0 + tx] =
        (__bf16)(tile[tx][ty + i * 8] * s);
}

// ---------- fused QKV projection: 64 rows x all 384 cols per block, 8 waves ----------
__global__ __launch_bounds__(512, 4) void k_proj(
    const float* __restrict__ x, const __bf16* __restrict__ Wt,
    __bf16* __restrict__ qk, __bf16* __restrict__ Vt)
{
  const int tid  = threadIdx.x;
  const int lane = tid & 63, wid = tid >> 6;
  const int lr = lane & 15, g = lane >> 4;
  const int m0 = blockIdx.x * 64;

  __shared__ __bf16 As[2][2][64][32];  // [buf][kk][row][col], col XOR-swizzled

  const int srow = tid >> 3;            // 0..63
  const int cs   = (tid & 7) * 8;       // 0..56
  const int skk  = cs >> 5;
  const int scol = cs & 31;
  const int sswz = ((srow >> 1) & 3) << 3;
  const float* xrow = x + (size_t)(m0 + srow) * 1024 + cs;

  const int nbase = wid * 48;           // wave owns 48 N-cols (3 frags)
  f32x4 acc[4][3] = {};

  float4 an0 = *(const float4*)(xrow);
  float4 an1 = *(const float4*)(xrow + 4);

  for (int kt = 0; kt < 16; ++kt) {
    const int buf = kt & 1;
    *(bf16x8*)&As[buf][skk][srow][scol ^ sswz] = pack8(an0, an1);
    if (kt < 15) {                      // prefetch next A-tile (stays in flight: no vmcnt drain)
      an0 = *(const float4*)(xrow + (kt + 1) * 64);
      an1 = *(const float4*)(xrow + (kt + 1) * 64 + 4);
    }
    asm volatile("s_waitcnt lgkmcnt(0)\n\ts_barrier" ::: "memory");
    const int k0 = kt * 64;
#pragma unroll
    for (int kk = 0; kk < 2; ++kk) {
      bf16x8 af[4];
#pragma unroll
      for (int i = 0; i < 4; ++i) {
        const int row = i * 16 + lr;
        af[i] = *(const bf16x8*)&As[buf][kk][row][(g * 8) ^ (((row >> 1) & 3) << 3)];
      }
#pragma unroll
      for (int j = 0; j < 3; ++j) {
        const bf16x8 bfr = *(const bf16x8*)(
            Wt + (size_t)(nbase + j * 16 + lr) * 1024 + k0 + kk * 32 + g * 8);
#pragma unroll
        for (int i = 0; i < 4; ++i)
          acc[i][j] = MFMA16(af[i], bfr, acc[i][j]);
      }
    }
  }

  const int b  = m0 >> 11;
  const int t0 = m0 & 2047;
#pragma unroll
  for (int j = 0; j < 3; ++j) {
    const int n = nbase + j * 16 + lr;
    if (nbase + j * 16 < 256) {
#pragma unroll
      for (int i = 0; i < 4; ++i) {
        const size_t mr = (size_t)(m0 + i * 16 + g * 4);
#pragma unroll
        for (int rr = 0; rr < 4; ++rr)
          qk[(mr + rr) * 256 + n] = (__bf16)acc[i][j][rr];
      }
    } else {
      const int d = n - 256;
#pragma unroll
      for (int i = 0; i < 4; ++i) {
        const int t = t0 + i * 16 + g * 4;
        bf16x4 pv;
        pv[0] = (__bf16)acc[i][j][0]; pv[1] = (__bf16)acc[i][j][1];
        pv[2] = (__bf16)acc[i][j][2]; pv[3] = (__bf16)acc[i][j][3];
        *(bf16x4*)(Vt + ((size_t)(b * 128 + d)) * 2048 + t) = pv;
      }
    }
  }
}

// ---------- causal flash attention ----------
// Block = (batch, 16 q-rows); 4 waves split KV tiles round-robin (partial m,l,o),
// LDS combine at the end. Swapped-operand MFMA: lane owns one q-row (q = q0+lr).
__global__ __launch_bounds__(256, 4) void k_attn(
    const __bf16* __restrict__ qk, const __bf16* __restrict__ Vt,
    float* __restrict__ out)
{
  const int tid  = threadIdx.x;
  const int lane = tid & 63, wid = tid >> 6;
  const int lr = lane & 15, g = lane >> 4;
  const int b  = blockIdx.y;
  const int q0 = (int)(gridDim.x - 1 - blockIdx.x) * 16;  // heavy blocks first

  __shared__ float Lo[4][16][132];   // [wave][q][d] fp32 partial O
  __shared__ float Lml[4][16][2];    // [wave][q][{m,l}]

  const __bf16* qkb = qk + (size_t)b * 2048 * 256;
  const __bf16* vtb = Vt + (size_t)b * 128 * 2048;

  // Q as B-frag: lane (lr,g) holds Q[q0+lr][d4*32+g*8 ..+7]
  bf16x8 qf[4];
#pragma unroll
  for (int d4 = 0; d4 < 4; ++d4)
    qf[d4] = *(const bf16x8*)(qkb + (size_t)(q0 + lr) * 256 + d4 * 32 + g * 8);

  f32x4 o[8] = {};                   // o[dt][rr] = O[q0+lr][dt*16+g*4+rr]
  float m = -1e30f, l = 0.0f;

  const int ntiles = (q0 >> 5) + 1;
  for (int t = wid; t < ntiles; t += 4) {
    const int kv0 = t << 5;
    bf16x8 kf0[4], kf1[4];
#pragma unroll
    for (int d4 = 0; d4 < 4; ++d4) {
      kf0[d4] = *(const bf16x8*)(qkb + (size_t)(kv0 + lr)      * 256 + 128 + d4 * 32 + g * 8);
      kf1[d4] = *(const bf16x8*)(qkb + (size_t)(kv0 + 16 + lr) * 256 + 128 + d4 * 32 + g * 8);
    }
    f32x4 s0 = {}, s1 = {};
#pragma unroll
    for (int d4 = 0; d4 < 4; ++d4) {
      s0 = MFMA16(kf0[d4], qf[d4], s0);   // lane holds q=lr, kv=kv0+g*4+rr
      s1 = MFMA16(kf1[d4], qf[d4], s1);   // kv=kv0+16+g*4+rr
    }
    bf16x8 vf[8];
#pragma unroll
    for (int dt = 0; dt < 8; ++dt)
      vf[dt] = *(const bf16x8*)(vtb + (size_t)(dt * 16 + lr) * 2048 + kv0 + g * 8);

    if (kv0 + 31 > q0) {               // diagonal tile: causal mask
      const int qrow = q0 + lr;
#pragma unroll
      for (int rr = 0; rr < 4; ++rr) {
        if (kv0 + g * 4 + rr > qrow)      s0[rr] = -1e30f;
        if (kv0 + 16 + g * 4 + rr > qrow) s1[rr] = -1e30f;
      }
    }
    float mx = fmaxf(fmaxf(fmaxf(s0[0], s0[1]), fmaxf(s0[2], s0[3])),
                     fmaxf(fmaxf(s1[0], s1[1]), fmaxf(s1[2], s1[3])));
    mx = fmaxf(mx, __shfl_xor(mx, 16));
    mx = fmaxf(mx, __shfl_xor(mx, 32));
    const float mnew = fmaxf(m, mx);
    const float al = exp2fast((m - mnew) * LOG2E);
    float p[8];
#pragma unroll
    for (int rr = 0; rr < 4; ++rr) {
      p[rr]     = exp2fast((s0[rr] - mnew) * LOG2E);
      p[4 + rr] = exp2fast((s1[rr] - mnew) * LOG2E);
    }
    float ps = ((p[0] + p[1]) + (p[2] + p[3])) + ((p[4] + p[5]) + (p[6] + p[7]));
    ps += __shfl_xor(ps, 16);
    ps += __shfl_xor(ps, 32);
    l = l * al + ps;
    m = mnew;

    // P^T B-frag redistribution. Source lane (lr,g') holds, for q-row q0+lr:
    //   c0=(kv g'*4+0,1) c1=(kv g'*4+2,3) c2=(kv 16+g'*4+0,1) c3=(kv 16+g'*4+2,3)
    // Target (lr,g) needs kv g*8..g*8+7 = lo-words (g<2) or hi-words (g>=2) of
    // source lanes lr+(g&1)*32 and lr+(g&1)*32+16. Publish ALL four words (8
    // bpermutes), select lo/hi at the target — one bpermute channel per word,
    // so no source serves two targets with different halves.
    const u32 c0 = pkbf16(p[0], p[1]), c1 = pkbf16(p[2], p[3]);
    const u32 c2 = pkbf16(p[4], p[5]), c3 = pkbf16(p[6], p[7]);
    const int srcA = (lr + ((g & 1) << 5)) << 2;   // byte addr of 1st source lane
    const u32 lo0 = (u32)__builtin_amdgcn_ds_bpermute(srcA,      (int)c0);
    const u32 lo1 = (u32)__builtin_amdgcn_ds_bpermute(srcA,      (int)c1);
    const u32 hi0 = (u32)__builtin_amdgcn_ds_bpermute(srcA,      (int)c2);
    const u32 hi1 = (u32)__builtin_amdgcn_ds_bpermute(srcA,      (int)c3);
    const u32 lo2 = (u32)__builtin_amdgcn_ds_bpermute(srcA + 64, (int)c0);
    const u32 lo3 = (u32)__builtin_amdgcn_ds_bpermute(srcA + 64, (int)c1);
    const u32 hi2 = (u32)__builtin_amdgcn_ds_bpermute(srcA + 64, (int)c2);
    const u32 hi3 = (u32)__builtin_amdgcn_ds_bpermute(srcA + 64, (int)c3);
    const bool hi = (g & 2) != 0;
    union { u32 u[4]; bf16x8 v; } pu;
    pu.u[0] = hi ? hi0 : lo0;
    pu.u[1] = hi ? hi1 : lo1;
    pu.u[2] = hi ? hi2 : lo2;
    pu.u[3] = hi ? hi3 : lo3;
    const bf16x8 pb = pu.v;

#pragma unroll
    for (int dt = 0; dt < 8; ++dt) {
#pragma unroll
      for (int rr = 0; rr < 4; ++rr) o[dt][rr] *= al;   // per-lane scalar (one q-row)
    }
#pragma unroll
    for (int dt = 0; dt < 8; ++dt)
      o[dt] = MFMA16(vf[dt], pb, o[dt]);   // O^T[d][q] += V^T-frag x P^T-frag
  }

  // write partials
#pragma unroll
  for (int dt = 0; dt < 8; ++dt)
    *(f32x4*)&Lo[wid][lr][dt * 16 + g * 4] = o[dt];
  if (lane < 16) { Lml[wid][lr][0] = m; Lml[wid][lr][1] = l; }
  __syncthreads();

  // combine: 256 threads over 16 rows x 128 cols
  const int row = tid >> 4, cg = tid & 15;
  float mw[4], lw[4];
#pragma unroll
  for (int w = 0; w < 4; ++w) { mw[w] = Lml[w][row][0]; lw[w] = Lml[w][row][1]; }
  const float M = fmaxf(fmaxf(mw[0], mw[1]), fmaxf(mw[2], mw[3]));
  float wt[4], L = 0.0f;
#pragma unroll
  for (int w = 0; w < 4; ++w) { wt[w] = exp2fast((mw[w] - M) * LOG2E); L += lw[w] * wt[w]; }
  const float inv = 1.0f / L;
  f32x4 acc0 = {}, acc1 = {};
#pragma unroll
  for (int w = 0; w < 4; ++w) {
    const f32x4 v0 = *(const f32x4*)&Lo[w][row][cg * 8];
    const f32x4 v1 = *(const f32x4*)&Lo[w][row][cg * 8 + 4];
    acc0 += v0 * wt[w];
    acc1 += v1 * wt[w];
  }
  float* orow = out + ((size_t)b * 2048 + q0 + row) * 128 + cg * 8;
  *(f32x4*)orow       = acc0 * inv;
  *(f32x4*)(orow + 4) = acc1 * inv;
}

extern "C" void kernel_launch(void* const* d_in, const int* in_sizes, int n_in,
                              void* d_out, int out_size, void* d_ws, size_t ws_size,
                              hipStream_t stream) {
  const float* x  = (const float*)d_in[0];
  const float* Wq = (const float*)d_in[1];
  const float* Wk = (const float*)d_in[2];
  const float* Wv = (const float*)d_in[3];
  float* out = (float*)d_out;

  char* ws = (char*)d_ws;
  __bf16* Wt  = (__bf16*)(ws);
  __bf16* qkb = (__bf16*)(ws + 786432);
  __bf16* Vt  = (__bf16*)(ws + 786432 + 16777216);

  k_build_wt<<<dim3(32, 4, 3), dim3(32, 8), 0, stream>>>(Wq, Wk, Wv, Wt);
  k_proj    <<<dim3(512),      dim3(512),   0, stream>>>(x, Wt, qkb, Vt);
  k_attn    <<<dim3(128, 16),  dim3(256),   0, stream>>>(qkb, Vt, out);
}

// Round 4
// 313.409 us; speedup vs baseline: 1.5555x; 1.2687x over previous
//
#include <hip/hip_runtime.h>
#include <hip/hip_bf16.h>
#include <stdint.h>

// Head: B=16, T=2048, C=1024, H=128. out fp32 [B,T,H].
// ws: WtB bf16 [32][384][32]          (Wt tiled: WtB[k/32][n][k%32])
//   | QT  bf16 [16][128][4][16][32]   (Q tiled: [b][t/16][d/32][t%16][d%32])
//   | KT  bf16 [16][128][4][16][32]
//   | VT2 bf16 [16][8][64][16][32]    (V^T tiled: [b][d/16][kv/32][d%16][kv%32])

typedef __bf16 bf16x8 __attribute__((ext_vector_type(8)));
typedef __bf16 bf16x4 __attribute__((ext_vector_type(4)));
typedef float  f32x4  __attribute__((ext_vector_type(4)));
typedef uint32_t u32;

#define MFMA16(a, b, c) __builtin_amdgcn_mfma_f32_16x16x32_bf16((a), (b), (c), 0, 0, 0)
#define LOG2E 1.4426950408889634f

static __device__ __forceinline__ float exp2fast(float x) { return __builtin_exp2f(x); }

static __device__ __forceinline__ bf16x4 pack4(float4 a) {
  bf16x4 r;
  r[0] = (__bf16)a.x; r[1] = (__bf16)a.y; r[2] = (__bf16)a.z; r[3] = (__bf16)a.w;
  return r;
}

static __device__ __forceinline__ u32 pkbf16(float a, float b) {
  union { __bf16 h[2]; u32 u; } t;
  t.h[0] = (__bf16)a; t.h[1] = (__bf16)b;
  return t.u;
}

// ---------- WtB[c>>5][n][c&31] = W_{n/128}[c][n%128] (Wq scaled) ----------
__global__ __launch_bounds__(256) void k_build_wt(
    const float* __restrict__ Wq, const float* __restrict__ Wk,
    const float* __restrict__ Wv, __bf16* __restrict__ WtB)
{
  __shared__ float tile[32][33];
  const int tx = threadIdx.x, ty = threadIdx.y;
  const int c0 = blockIdx.x * 32, h0 = blockIdx.y * 32, w = blockIdx.z;
  const float* W = (w == 0) ? Wq : (w == 1) ? Wk : Wv;
  const float s = (w == 0) ? 0.08838834764831843f : 1.0f;
#pragma unroll
  for (int i = 0; i < 4; ++i)
    tile[ty + i * 8][tx] = W[(size_t)(c0 + ty + i * 8) * 128 + h0 + tx];
  __syncthreads();
#pragma unroll
  for (int i = 0; i < 4; ++i) {
    const int n = w * 128 + h0 + ty + i * 8;
    WtB[(size_t)blockIdx.x * 12288 + (size_t)n * 32 + tx] =
        (__bf16)(tile[tx][ty + i * 8] * s);   // value = W[c0+tx][h-part]
  }
}

// ---------- fused QKV projection: BM=64, BK=32, all 384 N-cols, 8 waves ----------
__global__ __launch_bounds__(512, 4) void k_proj(
    const float* __restrict__ x, const __bf16* __restrict__ WtB,
    __bf16* __restrict__ QT, __bf16* __restrict__ KT, __bf16* __restrict__ VT2)
{
  const int tid  = threadIdx.x;
  const int lane = tid & 63, wid = tid >> 6;
  const int lr = lane & 15, g = lane >> 4;
  const int m0 = blockIdx.x * 64;

  __shared__ __bf16 As[2][64][32];     // 8 KB, 16B-chunk XOR swizzle

  const int srow = tid >> 3;           // 0..63
  const int sc4  = (tid & 7) * 4;      // float col 0..28
  char* AsB = (char*)As;
  const int wbyte = (srow * 64 + sc4 * 2) ^ (((srow >> 1) & 3) << 4);
  const float* xrow = x + (size_t)(m0 + srow) * 1024 + sc4;

  const int nbase = wid * 48;
  const __bf16* wB = WtB + (size_t)(nbase + lr) * 32 + g * 8;

  f32x4 acc[4][3] = {};

  float4 xreg = *(const float4*)(xrow);
  bf16x8 bcur[3], bnext[3];
#pragma unroll
  for (int j = 0; j < 3; ++j)
    bcur[j] = *(const bf16x8*)(wB + (size_t)j * 512);

  for (int kt = 0; kt < 32; ++kt) {
    const int buf = kt & 1;
    *(bf16x4*)(AsB + buf * 4096 + wbyte) = pack4(xreg);
    if (kt < 31)
      xreg = *(const float4*)(xrow + (kt + 1) * 32);   // HBM prefetch (vmcnt stays open)
    asm volatile("s_waitcnt lgkmcnt(0)\n\ts_barrier" ::: "memory");

    bf16x8 af[4];
#pragma unroll
    for (int i = 0; i < 4; ++i) {
      const int row = i * 16 + lr;
      af[i] = *(const bf16x8*)(AsB + buf * 4096 +
                               (row * 64 + ((g * 16) ^ (((row >> 1) & 3) << 4))));
    }
    if (kt < 31) {                                     // L2 prefetch of next B-frags
      const __bf16* wn = wB + (size_t)(kt + 1) * 12288;
#pragma unroll
      for (int j = 0; j < 3; ++j)
        bnext[j] = *(const bf16x8*)(wn + (size_t)j * 512);
    }
#pragma unroll
    for (int j = 0; j < 3; ++j)
#pragma unroll
      for (int i = 0; i < 4; ++i)
        acc[i][j] = MFMA16(af[i], bcur[j], acc[i][j]);
#pragma unroll
    for (int j = 0; j < 3; ++j) bcur[j] = bnext[j];
  }

  // epilogue: tiled stores
  const int b = m0 >> 11;
#pragma unroll
  for (int j = 0; j < 3; ++j) {
    const int n = nbase + j * 16 + lr;
#pragma unroll
    for (int i = 0; i < 4; ++i) {
      const int m = m0 + i * 16 + g * 4;      // +rr
      const int tt = m & 2047;
#pragma unroll
      for (int rr = 0; rr < 4; ++rr) {
        const float v = acc[i][j][rr];
        if (n < 128) {
          QT[(size_t)b * 262144 + (size_t)((tt + rr) >> 4) * 2048 +
             (n >> 5) * 512 + ((tt + rr) & 15) * 32 + (n & 31)] = (__bf16)v;
        } else if (n < 256) {
          const int nk = n - 128;
          KT[(size_t)b * 262144 + (size_t)((tt + rr) >> 4) * 2048 +
             (nk >> 5) * 512 + ((tt + rr) & 15) * 32 + (nk & 31)] = (__bf16)v;
        } else {
          const int d = n - 256, kv = tt + rr;
          VT2[(size_t)b * 262144 + (size_t)(d >> 4) * 32768 +
              (kv >> 5) * 512 + (d & 15) * 32 + (kv & 31)] = (__bf16)v;
        }
      }
    }
  }
}

// ---------- causal flash attention, software-pipelined ----------
// Block = (batch, 16 q-rows); 4 waves split 32-kv tiles round-robin; LDS combine.
// All fragment loads are contiguous 1KB wave-reads from the tiled layouts.
__global__ __launch_bounds__(256, 2) void k_attn(
    const __bf16* __restrict__ QT, const __bf16* __restrict__ KT,
    const __bf16* __restrict__ VT2, float* __restrict__ out)
{
  const int tid  = threadIdx.x;
  const int lane = tid & 63, wid = tid >> 6;
  const int lr = lane & 15, g = lane >> 4;
  const int b  = blockIdx.y;
  const int q0 = (int)(gridDim.x - 1 - blockIdx.x) * 16;  // heavy blocks first

  __shared__ float Lo[4][16][132];
  __shared__ float Lml[4][16][2];

  const __bf16* QTb = QT  + (size_t)b * 262144;
  const __bf16* KTb = KT  + (size_t)b * 262144;
  const __bf16* VTb = VT2 + (size_t)b * 262144;
  const int fo = lr * 32 + g * 8;      // per-lane offset within a 16x32 tile

  bf16x8 qf[4];
#pragma unroll
  for (int d4 = 0; d4 < 4; ++d4)
    qf[d4] = *(const bf16x8*)(QTb + (size_t)(q0 >> 4) * 2048 + d4 * 512 + fo);

  f32x4 o[8] = {};
  float m = -1e30f, l = 0.0f;

  const int ntiles = (q0 >> 5) + 1;
  bf16x8 kf0[4], kf1[4];
  if (wid < ntiles) {                  // preload tile t = wid
    const __bf16* kp = KTb + (size_t)wid * 4096 + fo;
#pragma unroll
    for (int d4 = 0; d4 < 4; ++d4) {
      kf0[d4] = *(const bf16x8*)(kp + d4 * 512);
      kf1[d4] = *(const bf16x8*)(kp + 2048 + d4 * 512);
    }
  }

  for (int t = wid; t < ntiles; t += 4) {
    const int kv0 = t << 5;
    // V for this tile: consumed after softmax (~400 cyc of cover)
    bf16x8 vf[8];
#pragma unroll
    for (int dt = 0; dt < 8; ++dt)
      vf[dt] = *(const bf16x8*)(VTb + (size_t)dt * 32768 + (size_t)(kv0 >> 5) * 512 + fo);
    // prefetch next K tile (consumed next iteration)
    bf16x8 kf0n[4], kf1n[4];
    const int tn = t + 4;
    if (tn < ntiles) {
      const __bf16* kp = KTb + (size_t)tn * 4096 + fo;
#pragma unroll
      for (int d4 = 0; d4 < 4; ++d4) {
        kf0n[d4] = *(const bf16x8*)(kp + d4 * 512);
        kf1n[d4] = *(const bf16x8*)(kp + 2048 + d4 * 512);
      }
    }

    f32x4 s0 = {}, s1 = {};
#pragma unroll
    for (int d4 = 0; d4 < 4; ++d4) {
      s0 = MFMA16(kf0[d4], qf[d4], s0);   // lane: q=q0+lr, kv=kv0+g*4+rr
      s1 = MFMA16(kf1[d4], qf[d4], s1);   // kv=kv0+16+g*4+rr
    }

    if (kv0 + 31 > q0) {               // diagonal tile: causal mask
      const int qrow = q0 + lr;
#pragma unroll
      for (int rr = 0; rr < 4; ++rr) {
        if (kv0 + g * 4 + rr > qrow)      s0[rr] = -1e30f;
        if (kv0 + 16 + g * 4 + rr > qrow) s1[rr] = -1e30f;
      }
    }
    float mx = fmaxf(fmaxf(fmaxf(s0[0], s0[1]), fmaxf(s0[2], s0[3])),
                     fmaxf(fmaxf(s1[0], s1[1]), fmaxf(s1[2], s1[3])));
    mx = fmaxf(mx, __shfl_xor(mx, 16));
    mx = fmaxf(mx, __shfl_xor(mx, 32));
    const float mnew = fmaxf(m, mx);
    const float al = exp2fast((m - mnew) * LOG2E);
    float p[8];
#pragma unroll
    for (int rr = 0; rr < 4; ++rr) {
      p[rr]     = exp2fast((s0[rr] - mnew) * LOG2E);
      p[4 + rr] = exp2fast((s1[rr] - mnew) * LOG2E);
    }
    float ps = ((p[0] + p[1]) + (p[2] + p[3])) + ((p[4] + p[5]) + (p[6] + p[7]));
    ps += __shfl_xor(ps, 16);
    ps += __shfl_xor(ps, 32);
    l = l * al + ps;
    m = mnew;

    // P^T B-frag redistribution: publish all 4 packed words, select lo/hi at target.
    const u32 c0 = pkbf16(p[0], p[1]), c1 = pkbf16(p[2], p[3]);
    const u32 c2 = pkbf16(p[4], p[5]), c3 = pkbf16(p[6], p[7]);
    const int srcA = (lr + ((g & 1) << 5)) << 2;
    const u32 lo0 = (u32)__builtin_amdgcn_ds_bpermute(srcA,      (int)c0);
    const u32 lo1 = (u32)__builtin_amdgcn_ds_bpermute(srcA,      (int)c1);
    const u32 hi0 = (u32)__builtin_amdgcn_ds_bpermute(srcA,      (int)c2);
    const u32 hi1 = (u32)__builtin_amdgcn_ds_bpermute(srcA,      (int)c3);
    const u32 lo2 = (u32)__builtin_amdgcn_ds_bpermute(srcA + 64, (int)c0);
    const u32 lo3 = (u32)__builtin_amdgcn_ds_bpermute(srcA + 64, (int)c1);
    const u32 hi2 = (u32)__builtin_amdgcn_ds_bpermute(srcA + 64, (int)c2);
    const u32 hi3 = (u32)__builtin_amdgcn_ds_bpermute(srcA + 64, (int)c3);
    const bool hi = (g & 2) != 0;
    union { u32 u[4]; bf16x8 v; } pu;
    pu.u[0] = hi ? hi0 : lo0;
    pu.u[1] = hi ? hi1 : lo1;
    pu.u[2] = hi ? hi2 : lo2;
    pu.u[3] = hi ? hi3 : lo3;
    const bf16x8 pb = pu.v;

#pragma unroll
    for (int dt = 0; dt < 8; ++dt) {
#pragma unroll
      for (int rr = 0; rr < 4; ++rr) o[dt][rr] *= al;
    }
#pragma unroll
    for (int dt = 0; dt < 8; ++dt)
      o[dt] = MFMA16(vf[dt], pb, o[dt]);

#pragma unroll
    for (int d4 = 0; d4 < 4; ++d4) { kf0[d4] = kf0n[d4]; kf1[d4] = kf1n[d4]; }
  }

#pragma unroll
  for (int dt = 0; dt < 8; ++dt)
    *(f32x4*)&Lo[wid][lr][dt * 16 + g * 4] = o[dt];
  if (lane < 16) { Lml[wid][lr][0] = m; Lml[wid][lr][1] = l; }
  __syncthreads();

  const int row = tid >> 4, cg = tid & 15;
  float mw[4], lw[4];
#pragma unroll
  for (int w = 0; w < 4; ++w) { mw[w] = Lml[w][row][0]; lw[w] = Lml[w][row][1]; }
  const float M = fmaxf(fmaxf(mw[0], mw[1]), fmaxf(mw[2], mw[3]));
  float wt[4], L = 0.0f;
#pragma unroll
  for (int w = 0; w < 4; ++w) { wt[w] = exp2fast((mw[w] - M) * LOG2E); L += lw[w] * wt[w]; }
  const float inv = 1.0f / L;
  f32x4 acc0 = {}, acc1 = {};
#pragma unroll
  for (int w = 0; w < 4; ++w) {
    const f32x4 v0 = *(const f32x4*)&Lo[w][row][cg * 8];
    const f32x4 v1 = *(const f32x4*)&Lo[w][row][cg * 8 + 4];
    acc0 += v0 * wt[w];
    acc1 += v1 * wt[w];
  }
  float* orow = out + ((size_t)b * 2048 + q0 + row) * 128 + cg * 8;
  *(f32x4*)orow       = acc0 * inv;
  *(f32x4*)(orow + 4) = acc1 * inv;
}

extern "C" void kernel_launch(void* const* d_in, const int* in_sizes, int n_in,
                              void* d_out, int out_size, void* d_ws, size_t ws_size,
                              hipStream_t stream) {
  const float* x  = (const float*)d_in[0];
  const float* Wq = (const float*)d_in[1];
  const float* Wk = (const float*)d_in[2];
  const float* Wv = (const float*)d_in[3];
  float* out = (float*)d_out;

  char* ws = (char*)d_ws;
  __bf16* WtB = (__bf16*)(ws);                       //    786,432 B
  __bf16* QT  = (__bf16*)(ws + 786432);              //  8,388,608 B
  __bf16* KT  = (__bf16*)(ws + 9175040);             //  8,388,608 B
  __bf16* VT2 = (__bf16*)(ws + 17563648);            //  8,388,608 B

  k_build_wt<<<dim3(32, 4, 3), dim3(32, 8), 0, stream>>>(Wq, Wk, Wv, WtB);
  k_proj    <<<dim3(512),      dim3(512),   0, stream>>>(x, WtB, QT, KT, VT2);
  k_attn    <<<dim3(128, 16),  dim3(256),   0, stream>>>(QT, KT, VT2, out);
}